// Round 17
// baseline (24.000 us; speedup 1.0000x reference)
//
#include <hip/hip_runtime.h>
#include <math.h>

#define IMG 256
#define NFACE 1000
#define NFP 1024               // padded face count; per tile: 4 waves x 256 faces
#define EPSF 1e-8f
#define LOG2E 1.44269504088896f
#define TCUT 16.0f             // drop contributions with u < -TCUT (<= 1.44*2^-16 each)
#define ACC_BREAK 25.0f        // once all lanes of a wave exceed: its tail < 2^-25
// Tile-center cull: max_tile u <= min_k c_k(center) + 3.5*sqrt(2)*LOG2E (=7.15)
#define CULL_M (-(TCUT + 7.15f))

// Static device scratch (graph-capture safe). SoA: 9 arrays of 1024 floats.
// Faces >= NFACE are self-rejecting pads (c2 = -1e9 -> never survive cull).
__device__ float g_soa[9][NFP];

// Broadcast lane s's register to all lanes (uniform s -> v_readlane).
__device__ __forceinline__ float bcast(float x, int s) {
    return __uint_as_float(__builtin_amdgcn_readlane(__float_as_uint(x), s));
}

// ---------------------------------------------------------------------------
// Kernel 1: per-face edge line coefficients (log2e-scaled), SoA.
// Also zeroes out[] (block 0). Degenerate faces (repeated vertex -> zero
// edge -> c==0 everywhere, face paints an infinite line band) need no
// special case under the center-distance cull.
// ---------------------------------------------------------------------------
__global__ __launch_bounds__(256) void k_coeff(const float* __restrict__ verts,
                                               const int* __restrict__ faces,
                                               const float* __restrict__ q,
                                               const float* __restrict__ t,
                                               const float* __restrict__ K,
                                               float* __restrict__ out) {
    int f = blockIdx.x * 256 + threadIdx.x;   // grid = 4 blocks -> f in [0,1024)
    if (blockIdx.x == 0 && threadIdx.x < IMG) out[threadIdx.x] = 0.f;
    if (f >= NFP) return;

    float c[9];
    if (f < NFACE) {
        float qw = q[0], qx = q[1], qy = q[2], qz = q[3];
        float qn = sqrtf(qw * qw + qx * qx + qy * qy + qz * qz + EPSF);
        qw /= qn; qx /= qn; qy /= qn; qz /= qn;
        float R00 = 1.f - 2.f * (qy * qy + qz * qz);
        float R01 = 2.f * (qx * qy - qw * qz);
        float R02 = 2.f * (qx * qz + qw * qy);
        float R10 = 2.f * (qx * qy + qw * qz);
        float R11 = 1.f - 2.f * (qx * qx + qz * qz);
        float R12 = 2.f * (qy * qz - qw * qx);
        float R20 = 2.f * (qx * qz - qw * qy);
        float R21 = 2.f * (qy * qz + qw * qx);
        float R22 = 1.f - 2.f * (qx * qx + qy * qy);
        float tx = t[0], ty = t[1], tz = t[2];
        float K00 = K[0], K02 = K[2], K11 = K[4], K12 = K[5];

        float X[3], Y[3];
#pragma unroll
        for (int k = 0; k < 3; ++k) {
            int vi = faces[f * 3 + k];
            float vx = verts[vi * 3 + 0];
            float vy = verts[vi * 3 + 1];
            float vz = verts[vi * 3 + 2];
            float cx = R00 * vx + R01 * vy + R02 * vz + tx;
            float cy = R10 * vx + R11 * vy + R12 * vz + ty;
            float cz = R20 * vx + R21 * vy + R22 * vz + tz;
            float z = cz + EPSF;
            X[k] = K00 * cx / z + K02;
            Y[k] = K11 * cy / z + K12;
        }

        float e01x = X[1] - X[0], e01y = Y[1] - Y[0];
        float e02x = X[2] - X[0], e02y = Y[2] - Y[0];
        float area2 = e01x * e02y - e01y * e02x;
        float s = (area2 >= 0.f) ? LOG2E : -LOG2E;

#pragma unroll
        for (int k = 0; k < 3; ++k) {
            int k1 = (k + 1) % 3;
            float ex = X[k1] - X[k];
            float ey = Y[k1] - Y[k];
            float inv = s / sqrtf(ex * ex + ey * ey + EPSF);
            c[k * 3 + 0] = -ey * inv;
            c[k * 3 + 1] = ex * inv;
            c[k * 3 + 2] = (ey * X[k] - ex * Y[k]) * inv;
        }
    } else {
        c[0] = 0.f; c[1] = 0.f; c[2] = -1e9f;
        c[3] = 0.f; c[4] = 0.f; c[5] = -1e9f;
        c[6] = 0.f; c[7] = 0.f; c[8] = -1e9f;
    }

#pragma unroll
    for (int k = 0; k < 9; ++k) g_soa[k][f] = c[k];
}

// ---------------------------------------------------------------------------
// Kernel 2: fused render+loss. R17 changes vs R16 (whose body is preserved):
//  (1) 256 blocks x 1024 threads (16 waves, 2 blocks/CU): the CP dispatch
//      ramp at 1024 wg was ~7-8 us of the single-shot time (R13 amortized
//      rep 11.3 us vs single-shot ~19). Each block owns 4 tiles at stride
//      256 (mixes image bands -> balanced blocks); 4 waves per tile x 256
//      faces each, per-round lazy loads + break as before.
//  (2) Branchless 2-wide mask walk: two set bits per iteration (second via
//      wave-uniform cselect, gated by 0/1 factor) -> half the taken
//      branches, two independent readlane+u chains in flight.
// ---------------------------------------------------------------------------
__global__ __launch_bounds__(1024, 2) void k_main(const float* __restrict__ image_ref,
                                                  float* __restrict__ out) {
    const int tid = threadIdx.x;
    const int wave = tid >> 6;        // 0..15
    const int lane = tid & 63;
    const int tlocal = wave >> 2;     // 0..3: which of this block's 4 tiles
    const int wgrp = wave & 3;        // 0..3: face group within the tile
    const int tile = blockIdx.x + (tlocal << 8);   // stride-256 tile mix
    const int x0 = (tile & 31) * 8, y0 = (tile >> 5) * 8;
    const int col = x0 + (lane & 7);
    const int row = y0 + (lane >> 3);
    const float px = col + 0.5f;
    const float py = row + 0.5f;
    const float tcx = x0 + 4.0f;      // pixel centers span +0.5..+7.5
    const float tcy = y0 + 4.0f;

    __shared__ float s_acc[16][64];

    float acc = 0.f;
    const int wbase = wgrp * 256;
    for (int r = 0; r < 4; ++r) {
        const int f = wbase + r * 64 + lane;
        float l0 = g_soa[0][f], l1 = g_soa[1][f], l2 = g_soa[2][f];
        float l3 = g_soa[3][f], l4 = g_soa[4][f], l5 = g_soa[5][f];
        float l6 = g_soa[6][f], l7 = g_soa[7][f], l8 = g_soa[8][f];
        float m = fminf(fminf(fmaf(tcx, l0, fmaf(tcy, l1, l2)),
                              fmaf(tcx, l3, fmaf(tcy, l4, l5))),
                        fmaf(tcx, l6, fmaf(tcy, l7, l8)));
        unsigned long long msk = __ballot(m > CULL_M);
        float p = 1.f;                      // running product of (1 + 2^-|u|)
        while (msk) {
            int s0 = __ffsll((unsigned long long)msk) - 1;
            msk &= msk - 1;
            bool has1 = (msk != 0);         // wave-uniform
            int s1 = has1 ? (__ffsll((unsigned long long)msk) - 1) : s0;
            msk &= msk - 1;
            float g1 = has1 ? 1.f : 0.f;

            float a0 = bcast(l0, s0), a1 = bcast(l1, s0), a2 = bcast(l2, s0);
            float b0 = bcast(l3, s0), b1 = bcast(l4, s0), b2 = bcast(l5, s0);
            float c0 = bcast(l6, s0), c1 = bcast(l7, s0), c2 = bcast(l8, s0);
            float A0 = bcast(l0, s1), A1 = bcast(l1, s1), A2 = bcast(l2, s1);
            float B0 = bcast(l3, s1), B1 = bcast(l4, s1), B2 = bcast(l5, s1);
            float C0 = bcast(l6, s1), C1 = bcast(l7, s1), C2 = bcast(l8, s1);

            float u0 = fminf(fminf(fmaf(px, a0, fmaf(py, a1, a2)),
                                   fmaf(px, b0, fmaf(py, b1, b2))),
                             fmaf(px, c0, fmaf(py, c1, c2)));
            float u1 = fminf(fminf(fmaf(px, A0, fmaf(py, A1, A2)),
                                   fmaf(px, B0, fmaf(py, B1, B2))),
                             fmaf(px, C0, fmaf(py, C1, C2)));

            acc += fmaxf(u0, 0.f) + fmaxf(u1, 0.f) * g1;
            float e0 = __builtin_amdgcn_exp2f(-fabsf(u0));
            float e1 = __builtin_amdgcn_exp2f(-fabsf(u1)) * g1;
            p = fmaf(p, e0, p);             // p *= (1 + e0)
            p = fmaf(p, e1, p);             // p *= (1 + e1)
        }
        acc += __builtin_amdgcn_logf(p);    // one log2 per round
        if (__all(acc > ACC_BREAK)) break;  // wave's remaining tail < 2^-25
    }

    // ---- combine the 4 waves of each tile, sil, loss, row atomic ----
    s_acc[wave][lane] = acc;
    __syncthreads();
    if (wgrp == 0) {                        // one wave per tile finishes it
        float tot = s_acc[wave][lane] + s_acc[wave + 1][lane] +
                    s_acc[wave + 2][lane] + s_acc[wave + 3][lane];
        float sil = 1.f - __builtin_amdgcn_exp2f(-tot);
        float d = sil - image_ref[row * IMG + col];
        float v = d * d;
        v += __shfl_xor(v, 1);   // sum over the 8 cols of this tile row
        v += __shfl_xor(v, 2);
        v += __shfl_xor(v, 4);
        if ((lane & 7) == 0) atomicAdd(&out[row], v * (1.f / 256.f));
    }
}

// ---------------------------------------------------------------------------
extern "C" void kernel_launch(void* const* d_in, const int* in_sizes, int n_in,
                              void* d_out, int out_size, void* d_ws, size_t ws_size,
                              hipStream_t stream) {
    const float* verts = (const float*)d_in[0];      // (1,1000,3) f32
    const int* faces = (const int*)d_in[1];          // (1,1000,3) i32
    const float* q = (const float*)d_in[2];          // (4,) f32
    const float* t = (const float*)d_in[3];          // (3,) f32
    const float* K = (const float*)d_in[4];          // (3,3) f32
    const float* image_ref = (const float*)d_in[5];  // (256,256) f32
    float* out = (float*)d_out;                      // (256,) f32

    k_coeff<<<NFP / 256, 256, 0, stream>>>(verts, faces, q, t, K, out);
    k_main<<<256, 1024, 0, stream>>>(image_ref, out);
}

// Round 18
// 21.642 us; speedup vs baseline: 1.1090x; 1.1090x over previous
//
#include <hip/hip_runtime.h>
#include <math.h>

#define IMG 256
#define NFACE 1000
#define NFP 1024               // padded face count; 4 waves x 256 faces (4 rounds)
#define NWAVE 4
#define EPSF 1e-8f
#define LOG2E 1.44269504088896f
#define TCUT 16.0f             // drop contributions with u < -TCUT (<= 1.44*2^-16 each)
#define ACC_BREAK 25.0f        // once all lanes of a wave exceed: its tail < 2^-25
// Tile-center cull: max_tile u <= min_k c_k(center) + 3.5*sqrt(2)*LOG2E (=7.15)
#define CULL_M (-(TCUT + 7.15f))

// Static device scratch (graph-capture safe). SoA: 9 arrays of 1024 floats.
// Faces >= NFACE are self-rejecting pads (c2 = -1e9 -> never survive cull).
__device__ float g_soa[9][NFP];

// Broadcast lane s's register to all lanes (uniform s -> v_readlane).
__device__ __forceinline__ float bcast(float x, int s) {
    return __uint_as_float(__builtin_amdgcn_readlane(__float_as_uint(x), s));
}

// ---------------------------------------------------------------------------
// Kernel 1: per-face edge line coefficients (log2e-scaled), SoA.
// Also zeroes out[] (block 0). Degenerate faces (repeated vertex -> zero
// edge -> c==0 everywhere, face paints an infinite line band) need no
// special case under the center-distance cull.
// ---------------------------------------------------------------------------
__global__ __launch_bounds__(256) void k_coeff(const float* __restrict__ verts,
                                               const int* __restrict__ faces,
                                               const float* __restrict__ q,
                                               const float* __restrict__ t,
                                               const float* __restrict__ K,
                                               float* __restrict__ out) {
    int f = blockIdx.x * 256 + threadIdx.x;   // grid = 4 blocks -> f in [0,1024)
    if (blockIdx.x == 0 && threadIdx.x < IMG) out[threadIdx.x] = 0.f;
    if (f >= NFP) return;

    float c[9];
    if (f < NFACE) {
        float qw = q[0], qx = q[1], qy = q[2], qz = q[3];
        float qn = sqrtf(qw * qw + qx * qx + qy * qy + qz * qz + EPSF);
        qw /= qn; qx /= qn; qy /= qn; qz /= qn;
        float R00 = 1.f - 2.f * (qy * qy + qz * qz);
        float R01 = 2.f * (qx * qy - qw * qz);
        float R02 = 2.f * (qx * qz + qw * qy);
        float R10 = 2.f * (qx * qy + qw * qz);
        float R11 = 1.f - 2.f * (qx * qx + qz * qz);
        float R12 = 2.f * (qy * qz - qw * qx);
        float R20 = 2.f * (qx * qz - qw * qy);
        float R21 = 2.f * (qy * qz + qw * qx);
        float R22 = 1.f - 2.f * (qx * qx + qy * qy);
        float tx = t[0], ty = t[1], tz = t[2];
        float K00 = K[0], K02 = K[2], K11 = K[4], K12 = K[5];

        float X[3], Y[3];
#pragma unroll
        for (int k = 0; k < 3; ++k) {
            int vi = faces[f * 3 + k];
            float vx = verts[vi * 3 + 0];
            float vy = verts[vi * 3 + 1];
            float vz = verts[vi * 3 + 2];
            float cx = R00 * vx + R01 * vy + R02 * vz + tx;
            float cy = R10 * vx + R11 * vy + R12 * vz + ty;
            float cz = R20 * vx + R21 * vy + R22 * vz + tz;
            float z = cz + EPSF;
            X[k] = K00 * cx / z + K02;
            Y[k] = K11 * cy / z + K12;
        }

        float e01x = X[1] - X[0], e01y = Y[1] - Y[0];
        float e02x = X[2] - X[0], e02y = Y[2] - Y[0];
        float area2 = e01x * e02y - e01y * e02x;
        float s = (area2 >= 0.f) ? LOG2E : -LOG2E;

#pragma unroll
        for (int k = 0; k < 3; ++k) {
            int k1 = (k + 1) % 3;
            float ex = X[k1] - X[k];
            float ey = Y[k1] - Y[k];
            float inv = s / sqrtf(ex * ex + ey * ey + EPSF);
            c[k * 3 + 0] = -ey * inv;
            c[k * 3 + 1] = ex * inv;
            c[k * 3 + 2] = (ey * X[k] - ex * Y[k]) * inv;
        }
    } else {
        c[0] = 0.f; c[1] = 0.f; c[2] = -1e9f;
        c[3] = 0.f; c[4] = 0.f; c[5] = -1e9f;
        c[6] = 0.f; c[7] = 0.f; c[8] = -1e9f;
    }

#pragma unroll
    for (int k = 0; k < 9; ++k) g_soa[k][f] = c[k];
}

// ---------------------------------------------------------------------------
// Kernel 2: fused render+loss. EXACTLY R16's structure and launch shape
// (1024 blocks x 256 threads - best known, 20.7 us) with ONE change: the
// survivor walk processes TWO mask bits per iteration. The second survivor
// is gated by a 0/1 factor (wave-uniform cselect, no extra branch); the two
// readlane->u chains are independent and interleave in the issue slots,
// halving taken-branch overhead and hiding ~half the per-survivor latency.
// ---------------------------------------------------------------------------
__global__ __launch_bounds__(256) void k_main(const float* __restrict__ image_ref,
                                              float* __restrict__ out) {
    const int tid = threadIdx.x;
    const int wave = tid >> 6;
    const int lane = tid & 63;
    const int x0 = blockIdx.x * 8, y0 = blockIdx.y * 8;
    const int col = x0 + (lane & 7);
    const int row = y0 + (lane >> 3);
    const float px = col + 0.5f;
    const float py = row + 0.5f;
    const float tcx = x0 + 4.0f;   // pixel centers span +0.5..+7.5
    const float tcy = y0 + 4.0f;

    __shared__ float s_acc[NWAVE][64];

    float acc = 0.f;
    const int wbase = wave * 256;
    for (int r = 0; r < 4; ++r) {
        const int f = wbase + r * 64 + lane;
        float l0 = g_soa[0][f], l1 = g_soa[1][f], l2 = g_soa[2][f];
        float l3 = g_soa[3][f], l4 = g_soa[4][f], l5 = g_soa[5][f];
        float l6 = g_soa[6][f], l7 = g_soa[7][f], l8 = g_soa[8][f];
        float m = fminf(fminf(fmaf(tcx, l0, fmaf(tcy, l1, l2)),
                              fmaf(tcx, l3, fmaf(tcy, l4, l5))),
                        fmaf(tcx, l6, fmaf(tcy, l7, l8)));
        unsigned long long msk = __ballot(m > CULL_M);
        float p = 1.f;                      // running product of (1 + 2^-|u|)
        while (msk) {
            int s0 = __ffsll((unsigned long long)msk) - 1;   // uniform
            msk &= msk - 1;
            bool has1 = (msk != 0);                          // uniform
            int s1 = has1 ? (__ffsll((unsigned long long)msk) - 1) : s0;
            msk &= msk - 1;
            float g1 = has1 ? 1.f : 0.f;

            float a0 = bcast(l0, s0), a1 = bcast(l1, s0), a2 = bcast(l2, s0);
            float b0 = bcast(l3, s0), b1 = bcast(l4, s0), b2 = bcast(l5, s0);
            float c0 = bcast(l6, s0), c1 = bcast(l7, s0), c2 = bcast(l8, s0);
            float A0 = bcast(l0, s1), A1 = bcast(l1, s1), A2 = bcast(l2, s1);
            float B0 = bcast(l3, s1), B1 = bcast(l4, s1), B2 = bcast(l5, s1);
            float C0 = bcast(l6, s1), C1 = bcast(l7, s1), C2 = bcast(l8, s1);

            float u0 = fminf(fminf(fmaf(px, a0, fmaf(py, a1, a2)),
                                   fmaf(px, b0, fmaf(py, b1, b2))),
                             fmaf(px, c0, fmaf(py, c1, c2)));
            float u1 = fminf(fminf(fmaf(px, A0, fmaf(py, A1, A2)),
                                   fmaf(px, B0, fmaf(py, B1, B2))),
                             fmaf(px, C0, fmaf(py, C1, C2)));

            acc += fmaxf(u0, 0.f) + fmaxf(u1, 0.f) * g1;
            float e0 = __builtin_amdgcn_exp2f(-fabsf(u0));
            float e1 = __builtin_amdgcn_exp2f(-fabsf(u1)) * g1;
            p = fmaf(p, e0, p);             // p *= (1 + e0)
            p = fmaf(p, e1, p);             // p *= (1 + e1)
        }
        acc += __builtin_amdgcn_logf(p);    // one log2 per round
        if (__all(acc > ACC_BREAK)) break;  // wave's remaining tail < 2^-25
    }

    // ---- combine waves, sil, sqdiff, row-reduce, atomic row partial ----
    s_acc[wave][lane] = acc;
    __syncthreads();
    if (wave == 0) {
        float tot = s_acc[0][lane] + s_acc[1][lane] +
                    s_acc[2][lane] + s_acc[3][lane];
        float sil = 1.f - __builtin_amdgcn_exp2f(-tot);
        float d = sil - image_ref[row * IMG + col];
        float v = d * d;
        v += __shfl_xor(v, 1);   // sum over the 8 cols of this tile row
        v += __shfl_xor(v, 2);
        v += __shfl_xor(v, 4);
        if ((lane & 7) == 0) atomicAdd(&out[row], v * (1.f / 256.f));
    }
}

// ---------------------------------------------------------------------------
extern "C" void kernel_launch(void* const* d_in, const int* in_sizes, int n_in,
                              void* d_out, int out_size, void* d_ws, size_t ws_size,
                              hipStream_t stream) {
    const float* verts = (const float*)d_in[0];      // (1,1000,3) f32
    const int* faces = (const int*)d_in[1];          // (1,1000,3) i32
    const float* q = (const float*)d_in[2];          // (4,) f32
    const float* t = (const float*)d_in[3];          // (3,) f32
    const float* K = (const float*)d_in[4];          // (3,3) f32
    const float* image_ref = (const float*)d_in[5];  // (256,256) f32
    float* out = (float*)d_out;                      // (256,) f32

    k_coeff<<<NFP / 256, 256, 0, stream>>>(verts, faces, q, t, K, out);
    k_main<<<dim3(IMG / 8, IMG / 8), 256, 0, stream>>>(image_ref, out);
}